// Round 9
// baseline (250.461 us; speedup 1.0000x reference)
//
#include <hip/hip_runtime.h>
#include <hip/hip_bf16.h>

// Problem constants (B,L,H,D) = (8,2048,8,64); sample_k = u = 40.
#define BB 8
#define LL 2048
#define HH 8
#define DD 64
#define HD 512      // H*D
#define SK 40       // sample_k
#define UU 40       // top-u
#define NCHUNK 16   // key chunks for flash-decode
#define CHUNK 128   // keys per chunk

typedef float v4f __attribute__((ext_vector_type(4)));

// ---------------- workspace layout (bytes) ----------------
static const size_t OFF_M     = 0;                 // B*H*L floats   = 512 KB
static const size_t OFF_TOP   = 512ull * 1024;     // B*H*40 ints    = 10 KB
static const size_t OFF_VPART = 528ull * 1024;     // 16*B*H*64 floats = 256 KB
static const size_t OFF_MPART = 784ull * 1024;     // B*H*40*16      = 160 KB
static const size_t OFF_SPART = 944ull * 1024;     // B*H*40*16      = 160 KB
static const size_t OFF_OPART = 1152ull * 1024;    // B*H*40*16*64   = 10 MB

// butterfly-add via DPP (VALU pipe). ctrl must be an ICE -> template param.
template <int CTRL>
__device__ __forceinline__ float dpp_add(float x) {
    int yi = __builtin_amdgcn_mov_dpp(__float_as_int(x), CTRL, 0xF, 0xF, true);
    return x + __int_as_float(yi);
}

// ============ kernel A v6.2: M[b,h,q] = max_s - mean_s of Q.Ksample ============
// Structure FINAL (round-6 verdict: L2-gather wall, ~68us whole). v6.2 is an
// INSTRUMENTATION split: two identical dispatches over q-halves (q0 = 0 /
// 1024), ~35us each, zero extra work. This pushes kA below any tail kernel
// >= 35us so the top-5 table finally shows the true #2 kernel (kE/kB/...)
// with exact counters. Do not "optimize" kA further.
__global__ __launch_bounds__(128, 4) void kA_sample_scores(
    const float* __restrict__ Q, const float* __restrict__ K,
    const int* __restrict__ IS, float* __restrict__ M, int q0)
{
    int blk = blockIdx.x;
    int b = blk & 7;                 // XCD pin: batch b -> XCD b (K[b]=4MB==L2)
    int q = (blk >> 3) + q0;
    int tid = threadIdx.x;
    int h = tid >> 4;
    int lane = tid & 15;

    const int* __restrict__ isq = IS + q * SK;   // block-uniform
    size_t base = (size_t)b * LL * HD;
    int off = h * DD + lane * 4;                 // per-thread, constant over s
    v4f qv = __builtin_nontemporal_load(
        (const v4f*)(Q + base + (size_t)q * HD + off));
    const float* __restrict__ Kb = K + base;

    // hoist all 40 indices into SGPRs (batched scalar loads, issued once)
    int sidx[SK];
#pragma unroll
    for (int s = 0; s < SK; ++s)
        sidx[s] = __builtin_amdgcn_readfirstlane(isq[s]);

    float mx = -1e30f, sm = 0.f;

#define KA_DOT(kv) { \
        float p = qv.x * kv.x + qv.y * kv.y + qv.z * kv.z + qv.w * kv.w; \
        p = dpp_add<0xB1>(p);    /* quad_perm xor1 */ \
        p = dpp_add<0x4E>(p);    /* quad_perm xor2 */ \
        p = dpp_add<0x141>(p);   /* row_half_mirror (== xor4 here) */ \
        p = dpp_add<0x140>(p);   /* row_mirror      (== xor8 here) */ \
        mx = fmaxf(mx, p); \
        sm += p; }

#pragma unroll
    for (int bt = 0; bt < 5; ++bt) {
        const int sb = bt * 8;
        v4f k0 = *(const v4f*)(Kb + (size_t)sidx[sb + 0] * HD + off);
        v4f k1 = *(const v4f*)(Kb + (size_t)sidx[sb + 1] * HD + off);
        v4f k2 = *(const v4f*)(Kb + (size_t)sidx[sb + 2] * HD + off);
        v4f k3 = *(const v4f*)(Kb + (size_t)sidx[sb + 3] * HD + off);
        v4f k4 = *(const v4f*)(Kb + (size_t)sidx[sb + 4] * HD + off);
        v4f k5 = *(const v4f*)(Kb + (size_t)sidx[sb + 5] * HD + off);
        v4f k6 = *(const v4f*)(Kb + (size_t)sidx[sb + 6] * HD + off);
        v4f k7 = *(const v4f*)(Kb + (size_t)sidx[sb + 7] * HD + off);
        asm volatile("" : "+v"(k0), "+v"(k1), "+v"(k2), "+v"(k3),
                          "+v"(k4), "+v"(k5), "+v"(k6), "+v"(k7));
        KA_DOT(k0) KA_DOT(k1) KA_DOT(k2) KA_DOT(k3)
        KA_DOT(k4) KA_DOT(k5) KA_DOT(k6) KA_DOT(k7)
    }
#undef KA_DOT

    if (lane == 0)
        M[((size_t)(b * HH + h)) * LL + q] = mx - sm * (1.0f / SK);
}

// ============ kernel B: top-40 of M[bh,:] via 3-level parallel radix select ============
__global__ __launch_bounds__(256) void kB_topk(
    const float* __restrict__ M, int* __restrict__ TopIdx)
{
    int bh = blockIdx.x;
    int tid = threadIdx.x;
    __shared__ unsigned keys[LL];        // 8 KB
    __shared__ int      hist[4096];      // 16 KB
    __shared__ int      sscan[256];      // 1 KB
    __shared__ unsigned ckeyA[2048];     // 8 KB
    __shared__ int      cidxA[2048];     // 8 KB
    __shared__ unsigned ckeyB[2048];     // 8 KB
    __shared__ int      cidxB[2048];     // 8 KB
    __shared__ int ctr[8]; // 0:sel 1:nA 2:nB 3:T 4:kprime 5:nExact

    const float* __restrict__ m = M + (size_t)bh * LL;
    for (int i = tid; i < 4096; i += 256) hist[i] = 0;
    if (tid < 8) ctr[tid] = 0;
    __syncthreads();

    // ---- L1 histogram (bits 31:20) ----
    for (int i = tid; i < LL; i += 256) {
        unsigned u = __float_as_uint(m[i]);
        u = (u & 0x80000000u) ? ~u : (u | 0x80000000u);   // monotone key
        keys[i] = u;
        atomicAdd(&hist[u >> 20], 1);
    }
    __syncthreads();
    // ---- L1 scan (target UU) ----
    {
        int p = 0;
#pragma unroll
        for (int j = 0; j < 16; ++j) p += hist[tid * 16 + j];
        sscan[tid] = p;
        __syncthreads();
        for (int o = 1; o < 256; o <<= 1) {
            int v = (tid + o < 256) ? sscan[tid + o] : 0;
            __syncthreads();
            sscan[tid] += v;
            __syncthreads();
        }
        int snext = (tid < 255) ? sscan[tid + 1] : 0;
        if (sscan[tid] >= UU && snext < UU) {
            int cum = snext;
            for (int bkt = tid * 16 + 15; bkt >= tid * 16; --bkt) {
                int c = hist[bkt];
                if (cum + c >= UU) { ctr[3] = bkt; ctr[4] = UU - cum; break; }
                cum += c;
            }
        }
    }
    __syncthreads();
    unsigned T1 = (unsigned)ctr[3];
    int k1 = ctr[4];
    // ---- L1 pass ----
    for (int i = tid; i < LL; i += 256) {
        unsigned u = keys[i];
        unsigned bkt = u >> 20;
        if (bkt > T1) {
            int p = atomicAdd(&ctr[0], 1);
            TopIdx[bh * UU + p] = i;
        } else if (bkt == T1) {
            int p = atomicAdd(&ctr[1], 1);
            ckeyA[p] = u; cidxA[p] = i;
        }
    }
    __syncthreads();
    int nA = ctr[1];

    // ---- L2 histogram (bits 19:8) ----
    for (int i = tid; i < 4096; i += 256) hist[i] = 0;
    __syncthreads();
    for (int i = tid; i < nA; i += 256)
        atomicAdd(&hist[(ckeyA[i] >> 8) & 0xFFF], 1);
    __syncthreads();
    // ---- L2 scan (target k1) ----
    {
        int p = 0;
#pragma unroll
        for (int j = 0; j < 16; ++j) p += hist[tid * 16 + j];
        sscan[tid] = p;
        __syncthreads();
        for (int o = 1; o < 256; o <<= 1) {
            int v = (tid + o < 256) ? sscan[tid + o] : 0;
            __syncthreads();
            sscan[tid] += v;
            __syncthreads();
        }
        int snext = (tid < 255) ? sscan[tid + 1] : 0;
        if (sscan[tid] >= k1 && snext < k1) {
            int cum = snext;
            for (int bkt = tid * 16 + 15; bkt >= tid * 16; --bkt) {
                int c = hist[bkt];
                if (cum + c >= k1) { ctr[3] = bkt; ctr[4] = k1 - cum; break; }
                cum += c;
            }
        }
    }
    __syncthreads();
    unsigned T2 = (unsigned)ctr[3];
    int k2 = ctr[4];
    // ---- L2 pass ----
    for (int i = tid; i < nA; i += 256) {
        unsigned u = ckeyA[i];
        unsigned bkt = (u >> 8) & 0xFFF;
        if (bkt > T2) {
            int p = atomicAdd(&ctr[0], 1);
            TopIdx[bh * UU + p] = cidxA[i];
        } else if (bkt == T2) {
            int p = atomicAdd(&ctr[2], 1);
            ckeyB[p] = u; cidxB[p] = cidxA[i];
        }
    }
    __syncthreads();
    int nB = ctr[2];

    // ---- L3 histogram (bits 7:0) ----
    for (int i = tid; i < 256; i += 256) hist[i] = 0;
    __syncthreads();
    for (int i = tid; i < nB; i += 256)
        atomicAdd(&hist[ckeyB[i] & 0xFF], 1);
    __syncthreads();
    // ---- L3 scan (target k2) ----
    {
        sscan[tid] = hist[tid];
        __syncthreads();
        for (int o = 1; o < 256; o <<= 1) {
            int v = (tid + o < 256) ? sscan[tid + o] : 0;
            __syncthreads();
            sscan[tid] += v;
            __syncthreads();
        }
        int snext = (tid < 255) ? sscan[tid + 1] : 0;
        if (sscan[tid] >= k2 && snext < k2) { ctr[3] = tid; ctr[4] = k2 - snext; }
    }
    __syncthreads();
    unsigned T3 = (unsigned)ctr[3];
    int k3 = ctr[4];
    // ---- L3 pass ----
    for (int i = tid; i < nB; i += 256) {
        unsigned u = ckeyB[i];
        unsigned bkt = u & 0xFF;
        if (bkt > T3) {
            int p = atomicAdd(&ctr[0], 1);
            TopIdx[bh * UU + p] = cidxB[i];
        } else if (bkt == T3) {
            int p = atomicAdd(&ctr[5], 1);
            cidxA[p] = cidxB[i];
        }
    }
    __syncthreads();
    // ---- exact-key ties: pick k3 smallest indices ----
    if (tid == 0) {
        int n = ctr[5];
        int basep = ctr[0];
        for (int r = 0; r < k3; ++r) {
            int bi = 1 << 30, bp = -1;
            for (int j = 0; j < n; ++j) {
                int id = cidxA[j];
                if (id >= 0 && id < bi) { bi = id; bp = j; }
            }
            TopIdx[bh * UU + basep + r] = bi;
            cidxA[bp] = -1;
        }
    }
}

// ============ kernel D: fill all output rows with mean(V)/L ============
// sums 16 per-chunk partials produced by kE (kC folded into kE, round 6).
__global__ __launch_bounds__(256) void kD_fill(
    const float* __restrict__ Vpart, float* __restrict__ out)
{
    size_t i4 = (size_t)blockIdx.x * 256 + threadIdx.x;
    size_t o = i4 * 4;
    int hd = (int)(o & (HD - 1));
    int b  = (int)(o >> 20);
    int h  = hd >> 6;
    int idx = (b * HH + h) * DD + (hd & 63);
    float4 acc = make_float4(0.f, 0.f, 0.f, 0.f);
#pragma unroll
    for (int c = 0; c < NCHUNK; ++c) {
        float4 v = *(const float4*)(Vpart + c * 4096 + idx);
        acc.x += v.x; acc.y += v.y; acc.z += v.z; acc.w += v.w;
    }
    const float sc = 1.0f / LL;
    float4 r; r.x = acc.x * sc; r.y = acc.y * sc; r.z = acc.z * sc; r.w = acc.w * sc;
    *(float4*)(out + o) = r;
}

// ============ kernel E v8: flash-decode partials + fused V column-sum ============
// (unchanged from round 8; see journal. XCD pin + kC fold were neutral but
// harmless; kept.)
__global__ __launch_bounds__(256, 4) void kE_attn_partial(
    const float* __restrict__ Q, const float* __restrict__ K, const float* __restrict__ V,
    const int* __restrict__ TopIdx,
    float* __restrict__ Opart, float* __restrict__ mpart, float* __restrict__ spart,
    float* __restrict__ Vpart)
{
    int bid = blockIdx.x;
    int b = bid & 7;                 // XCD pin
    int r9 = bid >> 3;
    int c = r9 & 15;
    int h = r9 >> 4;
    int bh = b * HH + h;
    int tid = threadIdx.x;

    __shared__ float Qs[UU * DD];            // 10 KB
    __shared__ float PT[UU][CHUNK + 4];      // 20.6 KB, transposed P, stride 132
    __shared__ float vred[16][DD];           // 4 KB, V column-sum partials
    __shared__ int   qidx[UU];
    __shared__ float mred[UU], sred[UU];

    if (tid < UU) qidx[tid] = TopIdx[bh * UU + tid];
    __syncthreads();

    size_t hbase  = (size_t)b * LL * HD + h * DD;
    size_t kcbase = hbase + (size_t)c * CHUNK * HD;

    for (int r = tid; r < UU * 16; r += 256) {
        int u = r >> 4, j = r & 15;
        *(float4*)(Qs + u * DD + j * 4) =
            *(const float4*)(Q + hbase + (size_t)qidx[u] * HD + j * 4);
    }
    __syncthreads();

    // ---- scores + in-register softmax ----
    {
        int w = tid >> 6;            // wave id: owns u in [w*10, w*10+10)
        int lane = tid & 63;         // key rows l0=lane, l1=lane+64
        const float* __restrict__ K0 = K + kcbase + (size_t)lane * HD;
        const float* __restrict__ K1 = K0 + (size_t)64 * HD;

        float d0[10], d1[10];
#pragma unroll
        for (int i = 0; i < 10; ++i) { d0[i] = 0.f; d1[i] = 0.f; }

#pragma unroll 1
        for (int qt = 0; qt < 4; ++qt) {        // 16 floats of d per quarter
            float4 ka[4], kb[4];
#pragma unroll
            for (int j = 0; j < 4; ++j) {
                ka[j] = *(const float4*)(K0 + qt * 16 + j * 4);
                kb[j] = *(const float4*)(K1 + qt * 16 + j * 4);
            }
#pragma unroll
            for (int j = 0; j < 4; ++j) {
#pragma unroll
                for (int uu = 0; uu < 10; ++uu) {
                    float4 qv = *(const float4*)(Qs + (w * 10 + uu) * DD + qt * 16 + j * 4);
                    d0[uu] += qv.x * ka[j].x + qv.y * ka[j].y + qv.z * ka[j].z + qv.w * ka[j].w;
                    d1[uu] += qv.x * kb[j].x + qv.y * kb[j].y + qv.z * kb[j].z + qv.w * kb[j].w;
                }
            }
        }

#pragma unroll
        for (int uu = 0; uu < 10; ++uu) {
            int u = w * 10 + uu;
            float x0 = d0[uu] * 0.125f;          // 1/sqrt(64)
            float x1 = d1[uu] * 0.125f;
            float m = fmaxf(x0, x1);
            m = fmaxf(m, __shfl_xor(m, 1));
            m = fmaxf(m, __shfl_xor(m, 2));
            m = fmaxf(m, __shfl_xor(m, 4));
            m = fmaxf(m, __shfl_xor(m, 8));
            m = fmaxf(m, __shfl_xor(m, 16));
            m = fmaxf(m, __shfl_xor(m, 32));     // max over all 128 keys
            float p0 = __expf(x0 - m);
            float p1 = __expf(x1 - m);
            PT[u][lane]      = p0;
            PT[u][lane + 64] = p1;
            float s = p0 + p1;
            s += __shfl_xor(s, 1);
            s += __shfl_xor(s, 2);
            s += __shfl_xor(s, 4);
            s += __shfl_xor(s, 8);
            s += __shfl_xor(s, 16);
            s += __shfl_xor(s, 32);              // sum over all 128 keys
            if (lane == 0) { mred[u] = m; sred[u] = s; }
        }
    }
    __syncthreads();   // PT + mred/sred ready

    // ---- PV + fused V column-sum ----
    {
        int dq = tid & 15, ug4 = tid >> 4;
        float4 acc[3];
#pragma unroll
        for (int i = 0; i < 3; ++i) acc[i] = make_float4(0.f, 0.f, 0.f, 0.f);
        float4 vsum = make_float4(0.f, 0.f, 0.f, 0.f);
        const float* __restrict__ Vb = V + kcbase + dq * 4;
        for (int l0 = 0; l0 < CHUNK; l0 += 8) {
            float4 v[8];
#pragma unroll
            for (int j = 0; j < 8; ++j)
                v[j] = *(const float4*)(Vb + (size_t)(l0 + j) * HD);
            if (ug4 == (l0 >> 3)) {              // owner group: V column-sum
#pragma unroll
                for (int j = 0; j < 8; ++j) {
                    vsum.x += v[j].x; vsum.y += v[j].y;
                    vsum.z += v[j].z; vsum.w += v[j].w;
                }
            }
#pragma unroll
            for (int i = 0; i < 3; ++i) {
                int u = ug4 + 16 * i;
                if (u < UU) {
                    float4 pa = *(const float4*)(&PT[u][l0]);
                    float4 pb = *(const float4*)(&PT[u][l0 + 4]);
                    acc[i].x += pa.x * v[0].x + pa.y * v[1].x + pa.z * v[2].x + pa.w * v[3].x
                              + pb.x * v[4].x + pb.y * v[5].x + pb.z * v[6].x + pb.w * v[7].x;
                    acc[i].y += pa.x * v[0].y + pa.y * v[1].y + pa.z * v[2].y + pa.w * v[3].y
                              + pb.x * v[4].y + pb.y * v[5].y + pb.z * v[6].y + pb.w * v[7].y;
                    acc[i].z += pa.x * v[0].z + pa.y * v[1].z + pa.z * v[2].z + pa.w * v[3].z
                              + pb.x * v[4].z + pb.y * v[5].z + pb.z * v[6].z + pb.w * v[7].z;
                    acc[i].w += pa.x * v[0].w + pa.y * v[1].w + pa.z * v[2].w + pa.w * v[3].w
                              + pb.x * v[4].w + pb.y * v[5].w + pb.z * v[6].w + pb.w * v[7].w;
                }
            }
        }
#pragma unroll
        for (int i = 0; i < 3; ++i) {
            int u = ug4 + 16 * i;
            if (u < UU) {
                size_t ob = (((size_t)(bh * UU + u)) * NCHUNK + c) * DD + dq * 4;
                *(float4*)(Opart + ob) = acc[i];
            }
        }
        *(float4*)(&vred[ug4][dq * 4]) = vsum;
    }
    __syncthreads();   // vred (and mred/sred) ready

    if (tid < DD) {    // one thread per d: reduce 16 groups, store chunk partial
        float s = 0.f;
#pragma unroll
        for (int g = 0; g < 16; ++g) s += vred[g][tid];
        Vpart[c * 4096 + bh * DD + tid] = s;
    }
    if (tid < UU) {
        mpart[(bh * UU + tid) * NCHUNK + c] = mred[tid];
        spart[(bh * UU + tid) * NCHUNK + c] = sred[tid];
    }
}

// ============ kernel F: combine chunk partials, scatter into output ============
__global__ __launch_bounds__(64) void kF_combine(
    const float* __restrict__ Opart, const float* __restrict__ mpart,
    const float* __restrict__ spart, const int* __restrict__ TopIdx,
    float* __restrict__ out)
{
    int g = blockIdx.x;            // bh*40 + u
    int bh = g / UU;
    int b = bh >> 3, h = bh & 7;
    int d = threadIdx.x;

    float m_i[NCHUNK];
    float Mx = -1e30f;
#pragma unroll
    for (int i = 0; i < NCHUNK; ++i) { m_i[i] = mpart[g * NCHUNK + i]; Mx = fmaxf(Mx, m_i[i]); }
    float S = 0.f, O = 0.f;
#pragma unroll
    for (int i = 0; i < NCHUNK; ++i) {
        float w = __expf(m_i[i] - Mx);
        S += w * spart[g * NCHUNK + i];
        O += w * Opart[((size_t)g * NCHUNK + i) * DD + d];
    }
    int qi = TopIdx[g];
    out[((size_t)b * LL + qi) * HD + h * DD + d] = O / S;
}

extern "C" void kernel_launch(void* const* d_in, const int* in_sizes, int n_in,
                              void* d_out, int out_size, void* d_ws, size_t ws_size,
                              hipStream_t stream) {
    const float* Q  = (const float*)d_in[0];
    const float* K  = (const float*)d_in[1];
    const float* V  = (const float*)d_in[2];
    const int*   IS = (const int*)d_in[3];
    float* out = (float*)d_out;
    char* ws = (char*)d_ws;

    float* M      = (float*)(ws + OFF_M);
    int*   TopIdx = (int*)(ws + OFF_TOP);
    float* Vpart  = (float*)(ws + OFF_VPART);
    float* mpart  = (float*)(ws + OFF_MPART);
    float* spart  = (float*)(ws + OFF_SPART);
    float* Opart  = (float*)(ws + OFF_OPART);

    kA_sample_scores<<<BB * (LL / 2), 128, 0, stream>>>(Q, K, IS, M, 0);
    kA_sample_scores<<<BB * (LL / 2), 128, 0, stream>>>(Q, K, IS, M, LL / 2);
    kB_topk<<<BB * HH, 256, 0, stream>>>(M, TopIdx);
    kE_attn_partial<<<BB * HH * NCHUNK, 256, 0, stream>>>(Q, K, V, TopIdx,
                                                          Opart, mpart, spart, Vpart);
    kD_fill<<<(BB * LL * HD) / (256 * 4), 256, 0, stream>>>(Vpart, out);
    kF_combine<<<BB * HH * UU, 64, 0, stream>>>(Opart, mpart, spart, TopIdx, out);
}

// Round 10
// 246.956 us; speedup vs baseline: 1.0142x; 1.0142x over previous
//
#include <hip/hip_runtime.h>
#include <hip/hip_bf16.h>

// Problem constants (B,L,H,D) = (8,2048,8,64); sample_k = u = 40.
#define BB 8
#define LL 2048
#define HH 8
#define DD 64
#define HD 512      // H*D
#define SK 40       // sample_k
#define UU 40       // top-u
#define NCHUNK 16   // key chunks for flash-decode
#define CHUNK 128   // keys per chunk

typedef float v4f __attribute__((ext_vector_type(4)));

// ---------------- workspace layout (bytes) ----------------
static const size_t OFF_M     = 0;                 // B*H*L floats   = 512 KB
static const size_t OFF_TOP   = 512ull * 1024;     // B*H*40 ints    = 10 KB
static const size_t OFF_VPART = 528ull * 1024;     // 16*B*H*64 floats = 256 KB
static const size_t OFF_MPART = 784ull * 1024;     // B*H*40*16      = 160 KB
static const size_t OFF_SPART = 944ull * 1024;     // B*H*40*16      = 160 KB
static const size_t OFF_OPART = 1152ull * 1024;    // B*H*40*16*64   = 10 MB

// butterfly-add via DPP (VALU pipe). ctrl must be an ICE -> template param.
template <int CTRL>
__device__ __forceinline__ float dpp_add(float x) {
    int yi = __builtin_amdgcn_mov_dpp(__float_as_int(x), CTRL, 0xF, 0xF, true);
    return x + __int_as_float(yi);
}

// ============ kernel A v6.2: M[b,h,q] = max_s - mean_s of Q.Ksample ============
// Structure FINAL (round-6 verdict: L2-gather wall). Split into two q-halves
// as INSTRUMENTATION (pushes kA to ~35us/dispatch so tail kernels surface in
// the top-5). Round 9 payoff: kE measured at 54.7us. Keep split until the
// tail is mapped; then merge back.
__global__ __launch_bounds__(128, 4) void kA_sample_scores(
    const float* __restrict__ Q, const float* __restrict__ K,
    const int* __restrict__ IS, float* __restrict__ M, int q0)
{
    int blk = blockIdx.x;
    int b = blk & 7;                 // XCD pin: batch b -> XCD b (K[b]=4MB==L2)
    int q = (blk >> 3) + q0;
    int tid = threadIdx.x;
    int h = tid >> 4;
    int lane = tid & 15;

    const int* __restrict__ isq = IS + q * SK;   // block-uniform
    size_t base = (size_t)b * LL * HD;
    int off = h * DD + lane * 4;                 // per-thread, constant over s
    v4f qv = __builtin_nontemporal_load(
        (const v4f*)(Q + base + (size_t)q * HD + off));
    const float* __restrict__ Kb = K + base;

    // hoist all 40 indices into SGPRs (batched scalar loads, issued once)
    int sidx[SK];
#pragma unroll
    for (int s = 0; s < SK; ++s)
        sidx[s] = __builtin_amdgcn_readfirstlane(isq[s]);

    float mx = -1e30f, sm = 0.f;

#define KA_DOT(kv) { \
        float p = qv.x * kv.x + qv.y * kv.y + qv.z * kv.z + qv.w * kv.w; \
        p = dpp_add<0xB1>(p);    /* quad_perm xor1 */ \
        p = dpp_add<0x4E>(p);    /* quad_perm xor2 */ \
        p = dpp_add<0x141>(p);   /* row_half_mirror (== xor4 here) */ \
        p = dpp_add<0x140>(p);   /* row_mirror      (== xor8 here) */ \
        mx = fmaxf(mx, p); \
        sm += p; }

#pragma unroll
    for (int bt = 0; bt < 5; ++bt) {
        const int sb = bt * 8;
        v4f k0 = *(const v4f*)(Kb + (size_t)sidx[sb + 0] * HD + off);
        v4f k1 = *(const v4f*)(Kb + (size_t)sidx[sb + 1] * HD + off);
        v4f k2 = *(const v4f*)(Kb + (size_t)sidx[sb + 2] * HD + off);
        v4f k3 = *(const v4f*)(Kb + (size_t)sidx[sb + 3] * HD + off);
        v4f k4 = *(const v4f*)(Kb + (size_t)sidx[sb + 4] * HD + off);
        v4f k5 = *(const v4f*)(Kb + (size_t)sidx[sb + 5] * HD + off);
        v4f k6 = *(const v4f*)(Kb + (size_t)sidx[sb + 6] * HD + off);
        v4f k7 = *(const v4f*)(Kb + (size_t)sidx[sb + 7] * HD + off);
        asm volatile("" : "+v"(k0), "+v"(k1), "+v"(k2), "+v"(k3),
                          "+v"(k4), "+v"(k5), "+v"(k6), "+v"(k7));
        KA_DOT(k0) KA_DOT(k1) KA_DOT(k2) KA_DOT(k3)
        KA_DOT(k4) KA_DOT(k5) KA_DOT(k6) KA_DOT(k7)
    }
#undef KA_DOT

    if (lane == 0)
        M[((size_t)(b * HH + h)) * LL + q] = mx - sm * (1.0f / SK);
}

// ============ kernel B: top-40 of M[bh,:] via 3-level parallel radix select ============
__global__ __launch_bounds__(256) void kB_topk(
    const float* __restrict__ M, int* __restrict__ TopIdx)
{
    int bh = blockIdx.x;
    int tid = threadIdx.x;
    __shared__ unsigned keys[LL];        // 8 KB
    __shared__ int      hist[4096];      // 16 KB
    __shared__ int      sscan[256];      // 1 KB
    __shared__ unsigned ckeyA[2048];     // 8 KB
    __shared__ int      cidxA[2048];     // 8 KB
    __shared__ unsigned ckeyB[2048];     // 8 KB
    __shared__ int      cidxB[2048];     // 8 KB
    __shared__ int ctr[8]; // 0:sel 1:nA 2:nB 3:T 4:kprime 5:nExact

    const float* __restrict__ m = M + (size_t)bh * LL;
    for (int i = tid; i < 4096; i += 256) hist[i] = 0;
    if (tid < 8) ctr[tid] = 0;
    __syncthreads();

    // ---- L1 histogram (bits 31:20) ----
    for (int i = tid; i < LL; i += 256) {
        unsigned u = __float_as_uint(m[i]);
        u = (u & 0x80000000u) ? ~u : (u | 0x80000000u);   // monotone key
        keys[i] = u;
        atomicAdd(&hist[u >> 20], 1);
    }
    __syncthreads();
    // ---- L1 scan (target UU) ----
    {
        int p = 0;
#pragma unroll
        for (int j = 0; j < 16; ++j) p += hist[tid * 16 + j];
        sscan[tid] = p;
        __syncthreads();
        for (int o = 1; o < 256; o <<= 1) {
            int v = (tid + o < 256) ? sscan[tid + o] : 0;
            __syncthreads();
            sscan[tid] += v;
            __syncthreads();
        }
        int snext = (tid < 255) ? sscan[tid + 1] : 0;
        if (sscan[tid] >= UU && snext < UU) {
            int cum = snext;
            for (int bkt = tid * 16 + 15; bkt >= tid * 16; --bkt) {
                int c = hist[bkt];
                if (cum + c >= UU) { ctr[3] = bkt; ctr[4] = UU - cum; break; }
                cum += c;
            }
        }
    }
    __syncthreads();
    unsigned T1 = (unsigned)ctr[3];
    int k1 = ctr[4];
    // ---- L1 pass ----
    for (int i = tid; i < LL; i += 256) {
        unsigned u = keys[i];
        unsigned bkt = u >> 20;
        if (bkt > T1) {
            int p = atomicAdd(&ctr[0], 1);
            TopIdx[bh * UU + p] = i;
        } else if (bkt == T1) {
            int p = atomicAdd(&ctr[1], 1);
            ckeyA[p] = u; cidxA[p] = i;
        }
    }
    __syncthreads();
    int nA = ctr[1];

    // ---- L2 histogram (bits 19:8) ----
    for (int i = tid; i < 4096; i += 256) hist[i] = 0;
    __syncthreads();
    for (int i = tid; i < nA; i += 256)
        atomicAdd(&hist[(ckeyA[i] >> 8) & 0xFFF], 1);
    __syncthreads();
    // ---- L2 scan (target k1) ----
    {
        int p = 0;
#pragma unroll
        for (int j = 0; j < 16; ++j) p += hist[tid * 16 + j];
        sscan[tid] = p;
        __syncthreads();
        for (int o = 1; o < 256; o <<= 1) {
            int v = (tid + o < 256) ? sscan[tid + o] : 0;
            __syncthreads();
            sscan[tid] += v;
            __syncthreads();
        }
        int snext = (tid < 255) ? sscan[tid + 1] : 0;
        if (sscan[tid] >= k1 && snext < k1) {
            int cum = snext;
            for (int bkt = tid * 16 + 15; bkt >= tid * 16; --bkt) {
                int c = hist[bkt];
                if (cum + c >= k1) { ctr[3] = bkt; ctr[4] = k1 - cum; break; }
                cum += c;
            }
        }
    }
    __syncthreads();
    unsigned T2 = (unsigned)ctr[3];
    int k2 = ctr[4];
    // ---- L2 pass ----
    for (int i = tid; i < nA; i += 256) {
        unsigned u = ckeyA[i];
        unsigned bkt = (u >> 8) & 0xFFF;
        if (bkt > T2) {
            int p = atomicAdd(&ctr[0], 1);
            TopIdx[bh * UU + p] = cidxA[i];
        } else if (bkt == T2) {
            int p = atomicAdd(&ctr[2], 1);
            ckeyB[p] = u; cidxB[p] = cidxA[i];
        }
    }
    __syncthreads();
    int nB = ctr[2];

    // ---- L3 histogram (bits 7:0) ----
    for (int i = tid; i < 256; i += 256) hist[i] = 0;
    __syncthreads();
    for (int i = tid; i < nB; i += 256)
        atomicAdd(&hist[ckeyB[i] & 0xFF], 1);
    __syncthreads();
    // ---- L3 scan (target k2) ----
    {
        sscan[tid] = hist[tid];
        __syncthreads();
        for (int o = 1; o < 256; o <<= 1) {
            int v = (tid + o < 256) ? sscan[tid + o] : 0;
            __syncthreads();
            sscan[tid] += v;
            __syncthreads();
        }
        int snext = (tid < 255) ? sscan[tid + 1] : 0;
        if (sscan[tid] >= k2 && snext < k2) { ctr[3] = tid; ctr[4] = k2 - snext; }
    }
    __syncthreads();
    unsigned T3 = (unsigned)ctr[3];
    int k3 = ctr[4];
    // ---- L3 pass ----
    for (int i = tid; i < nB; i += 256) {
        unsigned u = ckeyB[i];
        unsigned bkt = u & 0xFF;
        if (bkt > T3) {
            int p = atomicAdd(&ctr[0], 1);
            TopIdx[bh * UU + p] = cidxB[i];
        } else if (bkt == T3) {
            int p = atomicAdd(&ctr[5], 1);
            cidxA[p] = cidxB[i];
        }
    }
    __syncthreads();
    // ---- exact-key ties: pick k3 smallest indices ----
    if (tid == 0) {
        int n = ctr[5];
        int basep = ctr[0];
        for (int r = 0; r < k3; ++r) {
            int bi = 1 << 30, bp = -1;
            for (int j = 0; j < n; ++j) {
                int id = cidxA[j];
                if (id >= 0 && id < bi) { bi = id; bp = j; }
            }
            TopIdx[bh * UU + basep + r] = bi;
            cidxA[bp] = -1;
        }
    }
}

// ============ kernel D: fill all output rows with mean(V)/L ============
// sums 16 per-chunk partials produced by kE (kC folded into kE, round 6).
__global__ __launch_bounds__(256) void kD_fill(
    const float* __restrict__ Vpart, float* __restrict__ out)
{
    size_t i4 = (size_t)blockIdx.x * 256 + threadIdx.x;
    size_t o = i4 * 4;
    int hd = (int)(o & (HD - 1));
    int b  = (int)(o >> 20);
    int h  = hd >> 6;
    int idx = (b * HH + h) * DD + (hd & 63);
    float4 acc = make_float4(0.f, 0.f, 0.f, 0.f);
#pragma unroll
    for (int c = 0; c < NCHUNK; ++c) {
        float4 v = *(const float4*)(Vpart + c * 4096 + idx);
        acc.x += v.x; acc.y += v.y; acc.z += v.z; acc.w += v.w;
    }
    const float sc = 1.0f / LL;
    float4 r; r.x = acc.x * sc; r.y = acc.y * sc; r.z = acc.z * sc; r.w = acc.w * sc;
    *(float4*)(out + o) = r;
}

// ============ kernel E v9: flash-decode partials + fused V column-sum ============
// Round-9 counters: 54.7us, Occupancy 35%, LDS 36352B -> hard cap 4 blocks/CU
// with grid exactly 4/CU (zero scheduler slack; barrier stalls exposed).
// v9: alias vred (4KB) onto the head of Qs -- Qs's last read is before the
// scores->PV barrier, vred's first write is after it. LDS 36.35 -> 31.84KB
// -> 5 blocks/CU, giving a 5th resident block to hide barrier/latency stalls.
__global__ __launch_bounds__(256, 4) void kE_attn_partial(
    const float* __restrict__ Q, const float* __restrict__ K, const float* __restrict__ V,
    const int* __restrict__ TopIdx,
    float* __restrict__ Opart, float* __restrict__ mpart, float* __restrict__ spart,
    float* __restrict__ Vpart)
{
    int bid = blockIdx.x;
    int b = bid & 7;                 // XCD pin
    int r9 = bid >> 3;
    int c = r9 & 15;
    int h = r9 >> 4;
    int bh = b * HH + h;
    int tid = threadIdx.x;

    __shared__ float Qs[UU * DD];            // 10 KB (head 4KB re-used as vred in PV)
    __shared__ float PT[UU][CHUNK + 4];      // 20.6 KB, transposed P, stride 132
    __shared__ int   qidx[UU];
    __shared__ float mred[UU], sred[UU];
    float* vred = Qs;                        // [16][DD] alias, valid after scores barrier

    if (tid < UU) qidx[tid] = TopIdx[bh * UU + tid];
    __syncthreads();

    size_t hbase  = (size_t)b * LL * HD + h * DD;
    size_t kcbase = hbase + (size_t)c * CHUNK * HD;

    for (int r = tid; r < UU * 16; r += 256) {
        int u = r >> 4, j = r & 15;
        *(float4*)(Qs + u * DD + j * 4) =
            *(const float4*)(Q + hbase + (size_t)qidx[u] * HD + j * 4);
    }
    __syncthreads();

    // ---- scores + in-register softmax ----
    {
        int w = tid >> 6;            // wave id: owns u in [w*10, w*10+10)
        int lane = tid & 63;         // key rows l0=lane, l1=lane+64
        const float* __restrict__ K0 = K + kcbase + (size_t)lane * HD;
        const float* __restrict__ K1 = K0 + (size_t)64 * HD;

        float d0[10], d1[10];
#pragma unroll
        for (int i = 0; i < 10; ++i) { d0[i] = 0.f; d1[i] = 0.f; }

#pragma unroll 1
        for (int qt = 0; qt < 4; ++qt) {        // 16 floats of d per quarter
            float4 ka[4], kb[4];
#pragma unroll
            for (int j = 0; j < 4; ++j) {
                ka[j] = *(const float4*)(K0 + qt * 16 + j * 4);
                kb[j] = *(const float4*)(K1 + qt * 16 + j * 4);
            }
#pragma unroll
            for (int j = 0; j < 4; ++j) {
#pragma unroll
                for (int uu = 0; uu < 10; ++uu) {
                    float4 qv = *(const float4*)(Qs + (w * 10 + uu) * DD + qt * 16 + j * 4);
                    d0[uu] += qv.x * ka[j].x + qv.y * ka[j].y + qv.z * ka[j].z + qv.w * ka[j].w;
                    d1[uu] += qv.x * kb[j].x + qv.y * kb[j].y + qv.z * kb[j].z + qv.w * kb[j].w;
                }
            }
        }

#pragma unroll
        for (int uu = 0; uu < 10; ++uu) {
            int u = w * 10 + uu;
            float x0 = d0[uu] * 0.125f;          // 1/sqrt(64)
            float x1 = d1[uu] * 0.125f;
            float m = fmaxf(x0, x1);
            m = fmaxf(m, __shfl_xor(m, 1));
            m = fmaxf(m, __shfl_xor(m, 2));
            m = fmaxf(m, __shfl_xor(m, 4));
            m = fmaxf(m, __shfl_xor(m, 8));
            m = fmaxf(m, __shfl_xor(m, 16));
            m = fmaxf(m, __shfl_xor(m, 32));     // max over all 128 keys
            float p0 = __expf(x0 - m);
            float p1 = __expf(x1 - m);
            PT[u][lane]      = p0;
            PT[u][lane + 64] = p1;
            float s = p0 + p1;
            s += __shfl_xor(s, 1);
            s += __shfl_xor(s, 2);
            s += __shfl_xor(s, 4);
            s += __shfl_xor(s, 8);
            s += __shfl_xor(s, 16);
            s += __shfl_xor(s, 32);              // sum over all 128 keys
            if (lane == 0) { mred[u] = m; sred[u] = s; }
        }
    }
    __syncthreads();   // PT + mred/sred ready; Qs dead -> vred alias valid

    // ---- PV + fused V column-sum ----
    {
        int dq = tid & 15, ug4 = tid >> 4;
        float4 acc[3];
#pragma unroll
        for (int i = 0; i < 3; ++i) acc[i] = make_float4(0.f, 0.f, 0.f, 0.f);
        float4 vsum = make_float4(0.f, 0.f, 0.f, 0.f);
        const float* __restrict__ Vb = V + kcbase + dq * 4;
        for (int l0 = 0; l0 < CHUNK; l0 += 8) {
            float4 v[8];
#pragma unroll
            for (int j = 0; j < 8; ++j)
                v[j] = *(const float4*)(Vb + (size_t)(l0 + j) * HD);
            if (ug4 == (l0 >> 3)) {              // owner group: V column-sum
#pragma unroll
                for (int j = 0; j < 8; ++j) {
                    vsum.x += v[j].x; vsum.y += v[j].y;
                    vsum.z += v[j].z; vsum.w += v[j].w;
                }
            }
#pragma unroll
            for (int i = 0; i < 3; ++i) {
                int u = ug4 + 16 * i;
                if (u < UU) {
                    float4 pa = *(const float4*)(&PT[u][l0]);
                    float4 pb = *(const float4*)(&PT[u][l0 + 4]);
                    acc[i].x += pa.x * v[0].x + pa.y * v[1].x + pa.z * v[2].x + pa.w * v[3].x
                              + pb.x * v[4].x + pb.y * v[5].x + pb.z * v[6].x + pb.w * v[7].x;
                    acc[i].y += pa.x * v[0].y + pa.y * v[1].y + pa.z * v[2].y + pa.w * v[3].y
                              + pb.x * v[4].y + pb.y * v[5].y + pb.z * v[6].y + pb.w * v[7].y;
                    acc[i].z += pa.x * v[0].z + pa.y * v[1].z + pa.z * v[2].z + pa.w * v[3].z
                              + pb.x * v[4].z + pb.y * v[5].z + pb.z * v[6].z + pb.w * v[7].z;
                    acc[i].w += pa.x * v[0].w + pa.y * v[1].w + pa.z * v[2].w + pa.w * v[3].w
                              + pb.x * v[4].w + pb.y * v[5].w + pb.z * v[6].w + pb.w * v[7].w;
                }
            }
        }
#pragma unroll
        for (int i = 0; i < 3; ++i) {
            int u = ug4 + 16 * i;
            if (u < UU) {
                size_t ob = (((size_t)(bh * UU + u)) * NCHUNK + c) * DD + dq * 4;
                *(float4*)(Opart + ob) = acc[i];
            }
        }
        *(float4*)(&vred[ug4 * DD + dq * 4]) = vsum;
    }
    __syncthreads();   // vred (and mred/sred) ready

    if (tid < DD) {    // one thread per d: reduce 16 groups, store chunk partial
        float s = 0.f;
#pragma unroll
        for (int g = 0; g < 16; ++g) s += vred[g * DD + tid];
        Vpart[c * 4096 + bh * DD + tid] = s;
    }
    if (tid < UU) {
        mpart[(bh * UU + tid) * NCHUNK + c] = mred[tid];
        spart[(bh * UU + tid) * NCHUNK + c] = sred[tid];
    }
}

// ============ kernel F: combine chunk partials, scatter into output ============
__global__ __launch_bounds__(64) void kF_combine(
    const float* __restrict__ Opart, const float* __restrict__ mpart,
    const float* __restrict__ spart, const int* __restrict__ TopIdx,
    float* __restrict__ out)
{
    int g = blockIdx.x;            // bh*40 + u
    int bh = g / UU;
    int b = bh >> 3, h = bh & 7;
    int d = threadIdx.x;

    float m_i[NCHUNK];
    float Mx = -1e30f;
#pragma unroll
    for (int i = 0; i < NCHUNK; ++i) { m_i[i] = mpart[g * NCHUNK + i]; Mx = fmaxf(Mx, m_i[i]); }
    float S = 0.f, O = 0.f;
#pragma unroll
    for (int i = 0; i < NCHUNK; ++i) {
        float w = __expf(m_i[i] - Mx);
        S += w * spart[g * NCHUNK + i];
        O += w * Opart[((size_t)g * NCHUNK + i) * DD + d];
    }
    int qi = TopIdx[g];
    out[((size_t)b * LL + qi) * HD + h * DD + d] = O / S;
}

extern "C" void kernel_launch(void* const* d_in, const int* in_sizes, int n_in,
                              void* d_out, int out_size, void* d_ws, size_t ws_size,
                              hipStream_t stream) {
    const float* Q  = (const float*)d_in[0];
    const float* K  = (const float*)d_in[1];
    const float* V  = (const float*)d_in[2];
    const int*   IS = (const int*)d_in[3];
    float* out = (float*)d_out;
    char* ws = (char*)d_ws;

    float* M      = (float*)(ws + OFF_M);
    int*   TopIdx = (int*)(ws + OFF_TOP);
    float* Vpart  = (float*)(ws + OFF_VPART);
    float* mpart  = (float*)(ws + OFF_MPART);
    float* spart  = (float*)(ws + OFF_SPART);
    float* Opart  = (float*)(ws + OFF_OPART);

    kA_sample_scores<<<BB * (LL / 2), 128, 0, stream>>>(Q, K, IS, M, 0);
    kA_sample_scores<<<BB * (LL / 2), 128, 0, stream>>>(Q, K, IS, M, LL / 2);
    kB_topk<<<BB * HH, 256, 0, stream>>>(M, TopIdx);
    kE_attn_partial<<<BB * HH * NCHUNK, 256, 0, stream>>>(Q, K, V, TopIdx,
                                                          Opart, mpart, spart, Vpart);
    kD_fill<<<(BB * LL * HD) / (256 * 4), 256, 0, stream>>>(Vpart, out);
    kF_combine<<<BB * HH * UU, 64, 0, stream>>>(Opart, mpart, spart, TopIdx, out);
}